// Round 5
// baseline (277.801 us; speedup 1.0000x reference)
//
#include <hip/hip_runtime.h>
#include <math.h>

// Problem constants: B=32 batches, N=64 points, D=64 hidden.
#define BB 32
#define NN 64
#define DD 64
constexpr int MAT = BB * NN * NN;           // one (B,N,N) matrix = 131072 floats
constexpr int DJ_OFF = 6 * MAT;             // dj-pack: [b][i][jp][8] floats
constexpr int DJ_PER_B = 64 * 32 * 8;       // 16384 floats per batch
constexpr int POOLED_OFF = DJ_OFF + BB * DJ_PER_B;

typedef float v2f __attribute__((ext_vector_type(2)));

// ---------------------------------------------------------------------------
// Phase 1 (grid B*7): blocks m=0..5 compute the six bilinear attention
// matrices (scaled by -0.125*log2e); m4 = E_jl stored as exp2, PAIR-
// INTERLEAVED over j: [jp][l][2]; m5 = R_kl stored as exp2. Block m=6 builds
// the per-(i, j-pair) displacement pack {x0,x1,y0,y1,z0,z1,0,0} used via
// s_load in the main kernel.
// Key identity: q_i.k_j = aug(p_i)^T (W_A aug W_B aug^T) aug(p_j), 4x4 form.
// ---------------------------------------------------------------------------
__global__ __launch_bounds__(256) void simplex_phase1(
    const float* __restrict__ pc,
    const float* __restrict__ Wq,  const float* __restrict__ bq,
    const float* __restrict__ Wk1, const float* __restrict__ bk1,
    const float* __restrict__ Wk2, const float* __restrict__ bk2,
    const float* __restrict__ Wk3, const float* __restrict__ bk3,
    float* __restrict__ ws)
{
  const int blk = blockIdx.x;
  const int m   = blk % 7;
  const int b   = blk / 7;
  const int tid = threadIdx.x;

  __shared__ float M[4][4];
  __shared__ float P[NN][3];

  if (m < 6 && tid < 16) {
    int r = tid >> 2, c = tid & 3;
    const float *WA = Wq, *bA = bq, *WB = Wk1, *bB = bk1;
    switch (m) {
      case 0: WA = Wq;  bA = bq;  WB = Wk1; bB = bk1; break; // A_ij  (q,  k1)
      case 1: WA = Wq;  bA = bq;  WB = Wk2; bB = bk2; break; // A_ik  (q,  k2)
      case 2: WA = Wq;  bA = bq;  WB = Wk3; bB = bk3; break; // A_il  (q,  k3)
      case 3: WA = Wk2; bA = bk2; WB = Wk1; bB = bk1; break; // A_jkT (r=k, c=j)
      case 4: WA = Wk1; bA = bk1; WB = Wk3; bB = bk3; break; // E_jl  (r=j, c=l)
      case 5: WA = Wk2; bA = bk2; WB = Wk3; bB = bk3; break; // R_kl  (r=k, c=l)
    }
    float s = 0.f;
    for (int d = 0; d < DD; ++d) {
      float va = (r < 3) ? WA[r * DD + d] : bA[d];
      float vb = (c < 3) ? WB[c * DD + d] : bB[d];
      s = fmaf(va, vb, s);
    }
    M[r][c] = s;
  }
  if (tid < NN * 3) {
    ((float*)P)[tid] = pc[b * NN * 3 + tid];
  }
  __syncthreads();

  if (m == 6) {
    // dj-pack: [i][jp][8] = {x(2j),x(2j+1), y.., y.., z.., z.., 0, 0}
    for (int idx = tid; idx < DJ_PER_B; idx += 256) {
      int word = idx & 7;
      int jp   = (idx >> 3) & 31;
      int i    = idx >> 8;
      float v = 0.f;
      if (word < 6) {
        int axis = word >> 1;
        int j    = jp * 2 + (word & 1);
        v = P[j][axis] - P[i][axis];
      }
      ws[DJ_OFF + b * DJ_PER_B + idx] = v;
    }
    return;
  }

  const float scale2 = -0.125f * 1.4426950408889634f; // -scale*log2(e)

  for (int it = 0; it < 16; ++it) {
    int g = tid + 256 * it;        // 0..4095
    int r = g >> 6, c = g & 63;
    float ar0 = P[r][0], ar1 = P[r][1], ar2 = P[r][2];
    float ac0 = P[c][0], ac1 = P[c][1], ac2 = P[c][2];
    float t0 = fmaf(M[0][0], ac0, fmaf(M[0][1], ac1, fmaf(M[0][2], ac2, M[0][3])));
    float t1 = fmaf(M[1][0], ac0, fmaf(M[1][1], ac1, fmaf(M[1][2], ac2, M[1][3])));
    float t2 = fmaf(M[2][0], ac0, fmaf(M[2][1], ac1, fmaf(M[2][2], ac2, M[2][3])));
    float t3 = fmaf(M[3][0], ac0, fmaf(M[3][1], ac1, fmaf(M[3][2], ac2, M[3][3])));
    float v = fmaf(ar0, t0, fmaf(ar1, t1, fmaf(ar2, t2, t3))) * scale2;
    if (m == 4) {
      // exp2, pair-interleaved over j (=r): [jp][l][2]
      float e = __builtin_amdgcn_exp2f(v);
      ws[4 * MAT + b * 4096 + ((r >> 1) << 7) + (c << 1) + (r & 1)] = e;
    } else if (m == 5) {
      ws[5 * MAT + b * 4096 + g] = __builtin_amdgcn_exp2f(v);
    } else {
      ws[m * MAT + b * 4096 + g] = v;
    }
  }
  if (m == 0 && tid == 0) ws[POOLED_OFF + b] = 0.f;  // zero pooled[b]
}

// ---------------------------------------------------------------------------
// Main kernel: one block per (b, anchor i). LANE = l; j runs as PAIRS in the
// inner loop; waves split k (2-k unroll). Cross products live in per-lane
// registers; per-j uniform data comes from SMEM (s_load of dj-pack); only
// E (per-lane b64) and T (broadcast b64) touch the DS pipe in the hot loop.
//   x = 1 + T_jk * E_jl * (R_kl * w_il)   ;  gate = 1/x
//   det = d_j . (d_k x d_l)               ;  acc += gate*det^2 (paired rcp)
// R1/R2/R4 lesson: forcing v_pk_* via asm always regressed — gfx950 f32x2
// packed ops give no issue-rate win over 2 scalars; body stays pure C.
// THIS ROUND (single change vs R0): jp loop FULLY unrolled — every ds_read /
// s_load becomes base + compile-time offset immediate, deleting ~8-10
// addressing/loop instrs per jp (~15% of the issue budget).
// ---------------------------------------------------------------------------
__global__ __launch_bounds__(256, 8) void simplex_main(
    const float* __restrict__ pc,
    const float* __restrict__ ws_in,
    float* __restrict__ pooled)
{
  const int b    = blockIdx.x >> 6;
  const int i    = blockIdx.x & 63;
  const int tid  = threadIdx.x;
  const int lane = tid & 63;
  const int wu   = __builtin_amdgcn_readfirstlane(tid >> 6);

  __shared__ __align__(16) float sE[4096];   // E pair-interleaved [jp][l][2]
  __shared__ float sT[512];                  // per-wave T rows: [w][2][64]
  __shared__ float dX[NN], dY[NN], dZ[NN];
  __shared__ float wsum[4];

  const float* m0  = ws_in + 0 * MAT + (b * 64 + i) * 64; // A_ij[j]
  const float* m1  = ws_in + 1 * MAT + (b * 64 + i) * 64; // A_ik[k]
  const float* m2  = ws_in + 2 * MAT + (b * 64 + i) * 64; // A_il[l]
  const float* m3  = ws_in + 3 * MAT + b * 4096;          // A_jkT[k][j]
  const float* m4  = ws_in + 4 * MAT + b * 4096;          // E interleaved
  const float* m5  = ws_in + 5 * MAT + b * 4096;          // R_kl[k][l]
  const float* djp = ws_in + DJ_OFF + b * DJ_PER_B + i * 256; // [jp][8]

  // ---- stage E (16 KB) and displacements ----
  {
    const float4* src = (const float4*)m4;
    float4* dst = (float4*)sE;
    dst[tid]       = src[tid];
    dst[tid + 256] = src[tid + 256];
    dst[tid + 512] = src[tid + 512];
    dst[tid + 768] = src[tid + 768];
  }
  if (tid < 64) {
    const float pix = pc[(b * 64 + i) * 3 + 0];
    const float piy = pc[(b * 64 + i) * 3 + 1];
    const float piz = pc[(b * 64 + i) * 3 + 2];
    dX[tid] = pc[(b * 64 + tid) * 3 + 0] - pix;
    dY[tid] = pc[(b * 64 + tid) * 3 + 1] - piy;
    dZ[tid] = pc[(b * 64 + tid) * 3 + 2] - piz;
  }
  __syncthreads();

  const float dlx = dX[lane], dly = dY[lane], dlz = dZ[lane];
  const float wl  = __builtin_amdgcn_exp2f(m2[lane]); // exp2(A_il[l]) per-lane
  const float aij = m0[lane];                          // lane also plays j here
  float* sTw = sT + wu * 128;
  float acc = 0.f;

  for (int kk0 = 2 * wu; kk0 < 64; kk0 += 8) {
    const int kk = __builtin_amdgcn_readfirstlane(kk0);
    v2f cx2[2], cy2[2], cz2[2], mm2[2];
#pragma unroll
    for (int t = 0; t < 2; ++t) {
      const int k = kk + t;
      const float dkx = dX[k], dky = dY[k], dkz = dZ[k];  // broadcast
      const float cx = dky * dlz - dkz * dly;             // d_k x d_l (per-lane)
      const float cy = dkz * dlx - dkx * dlz;
      const float cz = dkx * dly - dky * dlx;
      cx2[t] = (v2f){cx, cx};
      cy2[t] = (v2f){cy, cy};
      cz2[t] = (v2f){cz, cz};
      const float mv = m5[k * 64 + lane] * wl;            // R_kl * w_il
      mm2[t] = (v2f){mv, mv};
      // T row for this k (lane plays j): exp2(a_ij + a_jk + a_ik)
      const float Tv = __builtin_amdgcn_exp2f(aij + m3[k * 64 + lane] + m1[k]);
      sTw[t * 64 + lane] = Tv;
    }
    // same-wave LDS write->read: compiler inserts lgkmcnt wait; no barrier.
#pragma unroll
    for (int jp = 0; jp < 32; ++jp) {
      const v2f xx = *(const v2f*)(djp + jp * 8 + 0);  // uniform -> s_load
      const v2f yy = *(const v2f*)(djp + jp * 8 + 2);
      const v2f zz = *(const v2f*)(djp + jp * 8 + 4);
      const v2f E01 = *(const v2f*)&sE[jp * 128 + lane * 2]; // per-lane b64
      v2f Tt[2];
      Tt[0] = *(const v2f*)&sTw[2 * jp];        // broadcast b64
      Tt[1] = *(const v2f*)&sTw[64 + 2 * jp];
#pragma unroll
      for (int t = 0; t < 2; ++t) {
        v2f e01 = E01 * mm2[t];
        v2f x01 = __builtin_elementwise_fma(Tt[t], e01, (v2f){1.f, 1.f});
        v2f det = __builtin_elementwise_fma(xx, cx2[t],
                    __builtin_elementwise_fma(yy, cy2[t], zz * cz2[t]));
        v2f d2  = det * det;
        float den = x01.x * x01.y;
        float rd  = __builtin_amdgcn_rcpf(den);
        float num = fmaf(d2.x, x01.y, d2.y * x01.x);
        acc = fmaf(num, rd, acc);
      }
    }
  }

  // reduce: lanes sum over l; waves sum over their k slices
  for (int s = 32; s; s >>= 1) acc += __shfl_xor(acc, s, 64);
  if (lane == 0) wsum[wu] = acc;
  __syncthreads();
  if (tid == 0) {
    float blocksum = wsum[0] + wsum[1] + wsum[2] + wsum[3];
    atomicAdd(&pooled[b], blocksum * (1.f / 16777216.f)); // / N^4
  }
}

// ---------------------------------------------------------------------------
// Final tiny MLP: out[b] = gelu_tanh(pooled[b]*W1 + b1) @ W2 + b2
// ---------------------------------------------------------------------------
__global__ void simplex_final(
    const float* __restrict__ pooled,
    const float* __restrict__ W1, const float* __restrict__ b1,
    const float* __restrict__ W2, const float* __restrict__ b2,
    float* __restrict__ out)
{
  int t = threadIdx.x;
  if (t < BB) {
    float x = pooled[t];
    float o = b2[0];
    for (int c = 0; c < 32; ++c) {
      float z  = fmaf(x, W1[c], b1[c]);
      float z3 = z * z * z;
      float y  = 0.7978845608028654f * fmaf(0.044715f, z3, z);
      float ay = fabsf(y);
      float e  = __builtin_amdgcn_exp2f(2.8853900817779268f * ay);
      float th = 1.f - 2.f / (e + 1.f);
      th = copysignf(th, y);
      float gl = 0.5f * z * (1.f + th);
      o = fmaf(gl, W2[c], o);
    }
    out[t] = o;
  }
}

// ---------------------------------------------------------------------------
extern "C" void kernel_launch(void* const* d_in, const int* in_sizes, int n_in,
                              void* d_out, int out_size, void* d_ws, size_t ws_size,
                              hipStream_t stream) {
  (void)in_sizes; (void)n_in; (void)out_size; (void)ws_size;
  const float* pc  = (const float*)d_in[0];
  const float* Wq  = (const float*)d_in[1];
  const float* bq  = (const float*)d_in[2];
  const float* Wk1 = (const float*)d_in[3];
  const float* bk1 = (const float*)d_in[4];
  const float* Wk2 = (const float*)d_in[5];
  const float* bk2 = (const float*)d_in[6];
  const float* Wk3 = (const float*)d_in[7];
  const float* bk3 = (const float*)d_in[8];
  const float* W1  = (const float*)d_in[9];
  const float* b1  = (const float*)d_in[10];
  const float* W2  = (const float*)d_in[11];
  const float* b2  = (const float*)d_in[12];

  float* ws     = (float*)d_ws;
  float* pooled = ws + POOLED_OFF;
  float* out    = (float*)d_out;

  hipLaunchKernelGGL(simplex_phase1, dim3(BB * 7), dim3(256), 0, stream,
                     pc, Wq, bq, Wk1, bk1, Wk2, bk2, Wk3, bk3, ws);
  hipLaunchKernelGGL(simplex_main, dim3(BB * NN), dim3(256), 0, stream,
                     pc, ws, pooled);
  hipLaunchKernelGGL(simplex_final, dim3(1), dim3(64), 0, stream,
                     pooled, W1, b1, W2, b2, out);
}

// Round 6
// 192.331 us; speedup vs baseline: 1.4444x; 1.4444x over previous
//
#include <hip/hip_runtime.h>
#include <math.h>

// Problem constants: B=32 batches, N=64 points, D=64 hidden.
#define BB 32
#define NN 64
#define DD 64
constexpr int MAT = BB * NN * NN;           // one (B,N,N) matrix = 131072 floats
constexpr int DJ_OFF = 6 * MAT;             // dj-pack: [b][i][jp][8] floats
constexpr int DJ_PER_B = 64 * 32 * 8;       // 16384 floats per batch
constexpr int POOLED_OFF = DJ_OFF + BB * DJ_PER_B;

typedef float v2f __attribute__((ext_vector_type(2)));

// ---------------------------------------------------------------------------
// Phase 1 (grid B*7): blocks m=0..5 compute the six bilinear attention
// matrices (scaled by -0.125*log2e); m4 = E_jl stored as exp2, PAIR-
// INTERLEAVED over j: [jp][l][2]; m5 = R_kl stored as exp2. Block m=6 builds
// the per-(i, j-pair) displacement pack {x0,x1,y0,y1,z0,z1,0,0}.
// Key identity: q_i.k_j = aug(p_i)^T (W_A aug W_B aug^T) aug(p_j), 4x4 form.
// ---------------------------------------------------------------------------
__global__ __launch_bounds__(256) void simplex_phase1(
    const float* __restrict__ pc,
    const float* __restrict__ Wq,  const float* __restrict__ bq,
    const float* __restrict__ Wk1, const float* __restrict__ bk1,
    const float* __restrict__ Wk2, const float* __restrict__ bk2,
    const float* __restrict__ Wk3, const float* __restrict__ bk3,
    float* __restrict__ ws)
{
  const int blk = blockIdx.x;
  const int m   = blk % 7;
  const int b   = blk / 7;
  const int tid = threadIdx.x;

  __shared__ float M[4][4];
  __shared__ float P[NN][3];

  if (m < 6 && tid < 16) {
    int r = tid >> 2, c = tid & 3;
    const float *WA = Wq, *bA = bq, *WB = Wk1, *bB = bk1;
    switch (m) {
      case 0: WA = Wq;  bA = bq;  WB = Wk1; bB = bk1; break; // A_ij  (q,  k1)
      case 1: WA = Wq;  bA = bq;  WB = Wk2; bB = bk2; break; // A_ik  (q,  k2)
      case 2: WA = Wq;  bA = bq;  WB = Wk3; bB = bk3; break; // A_il  (q,  k3)
      case 3: WA = Wk2; bA = bk2; WB = Wk1; bB = bk1; break; // A_jkT (r=k, c=j)
      case 4: WA = Wk1; bA = bk1; WB = Wk3; bB = bk3; break; // E_jl  (r=j, c=l)
      case 5: WA = Wk2; bA = bk2; WB = Wk3; bB = bk3; break; // R_kl  (r=k, c=l)
    }
    float s = 0.f;
    for (int d = 0; d < DD; ++d) {
      float va = (r < 3) ? WA[r * DD + d] : bA[d];
      float vb = (c < 3) ? WB[c * DD + d] : bB[d];
      s = fmaf(va, vb, s);
    }
    M[r][c] = s;
  }
  if (tid < NN * 3) {
    ((float*)P)[tid] = pc[b * NN * 3 + tid];
  }
  __syncthreads();

  if (m == 6) {
    // dj-pack: [i][jp][8] = {x(2j),x(2j+1), y.., y.., z.., z.., 0, 0}
    for (int idx = tid; idx < DJ_PER_B; idx += 256) {
      int word = idx & 7;
      int jp   = (idx >> 3) & 31;
      int i    = idx >> 8;
      float v = 0.f;
      if (word < 6) {
        int axis = word >> 1;
        int j    = jp * 2 + (word & 1);
        v = P[j][axis] - P[i][axis];
      }
      ws[DJ_OFF + b * DJ_PER_B + idx] = v;
    }
    return;
  }

  const float scale2 = -0.125f * 1.4426950408889634f; // -scale*log2(e)

  for (int it = 0; it < 16; ++it) {
    int g = tid + 256 * it;        // 0..4095
    int r = g >> 6, c = g & 63;
    float ar0 = P[r][0], ar1 = P[r][1], ar2 = P[r][2];
    float ac0 = P[c][0], ac1 = P[c][1], ac2 = P[c][2];
    float t0 = fmaf(M[0][0], ac0, fmaf(M[0][1], ac1, fmaf(M[0][2], ac2, M[0][3])));
    float t1 = fmaf(M[1][0], ac0, fmaf(M[1][1], ac1, fmaf(M[1][2], ac2, M[1][3])));
    float t2 = fmaf(M[2][0], ac0, fmaf(M[2][1], ac1, fmaf(M[2][2], ac2, M[2][3])));
    float t3 = fmaf(M[3][0], ac0, fmaf(M[3][1], ac1, fmaf(M[3][2], ac2, M[3][3])));
    float v = fmaf(ar0, t0, fmaf(ar1, t1, fmaf(ar2, t2, t3))) * scale2;
    if (m == 4) {
      // exp2, pair-interleaved over j (=r): [jp][l][2]
      float e = __builtin_amdgcn_exp2f(v);
      ws[4 * MAT + b * 4096 + ((r >> 1) << 7) + (c << 1) + (r & 1)] = e;
    } else if (m == 5) {
      ws[5 * MAT + b * 4096 + g] = __builtin_amdgcn_exp2f(v);
    } else {
      ws[m * MAT + b * 4096 + g] = v;
    }
  }
  if (m == 0 && tid == 0) ws[POOLED_OFF + b] = 0.f;  // zero pooled[b]
}

// ---------------------------------------------------------------------------
// Main kernel: one block per (b, anchor i). LANE = l; j runs as PAIRS in the
// inner loop; waves split k (2-k unroll). Cross products live in per-lane
// registers. SINGLE change vs R0 (best measured, 121.9us): the dj-pack is
// staged into LDS (sD) and read as uniform-address broadcast ds_read_b64 —
// the hot loop is now DS-only, so the compiler can use fine-grained
// lgkmcnt(N) instead of the lgkmcnt(0) drains forced by out-of-order s_load
// consumption (SMEM + DS share lgkmcnt).
//   x = 1 + T_jk * E_jl * (R_kl * w_il)   ;  gate = 1/x
//   det = d_j . (d_k x d_l)               ;  acc += gate*det^2 (paired rcp)
// R1/R2/R4 lesson: forced v_pk_* asm always regressed — body stays pure C.
// R5 lesson: full jp unroll spills (590 MB scratch traffic) — keep unroll 2.
// LDS = 16K (sE) + 1K (sD) + 2K (sT) + dXYZ + wsum = 20480 B -> 8 blocks/CU.
// ---------------------------------------------------------------------------
__global__ __launch_bounds__(256, 8) void simplex_main(
    const float* __restrict__ pc,
    const float* __restrict__ ws_in,
    float* __restrict__ pooled)
{
  const int b    = blockIdx.x >> 6;
  const int i    = blockIdx.x & 63;
  const int tid  = threadIdx.x;
  const int lane = tid & 63;
  const int wu   = __builtin_amdgcn_readfirstlane(tid >> 6);

  __shared__ __align__(16) float sE[4096];   // E pair-interleaved [jp][l][2]
  __shared__ __align__(16) float sD[256];    // dj-pack [jp][8]
  __shared__ float sT[512];                  // per-wave T rows: [w][2][64]
  __shared__ float dX[NN], dY[NN], dZ[NN];
  __shared__ float wsum[4];

  const float* m0  = ws_in + 0 * MAT + (b * 64 + i) * 64; // A_ij[j]
  const float* m1  = ws_in + 1 * MAT + (b * 64 + i) * 64; // A_ik[k]
  const float* m2  = ws_in + 2 * MAT + (b * 64 + i) * 64; // A_il[l]
  const float* m3  = ws_in + 3 * MAT + b * 4096;          // A_jkT[k][j]
  const float* m4  = ws_in + 4 * MAT + b * 4096;          // E interleaved
  const float* m5  = ws_in + 5 * MAT + b * 4096;          // R_kl[k][l]
  const float* djp = ws_in + DJ_OFF + b * DJ_PER_B + i * 256; // [jp][8]

  // ---- stage E (16 KB), dj-pack (1 KB), displacements ----
  {
    const float4* src = (const float4*)m4;
    float4* dst = (float4*)sE;
    dst[tid]       = src[tid];
    dst[tid + 256] = src[tid + 256];
    dst[tid + 512] = src[tid + 512];
    dst[tid + 768] = src[tid + 768];
  }
  if (tid < 64) {
    ((float4*)sD)[tid] = ((const float4*)djp)[tid];
  }
  if (tid >= 64 && tid < 128) {
    const int p = tid - 64;
    const float pix = pc[(b * 64 + i) * 3 + 0];
    const float piy = pc[(b * 64 + i) * 3 + 1];
    const float piz = pc[(b * 64 + i) * 3 + 2];
    dX[p] = pc[(b * 64 + p) * 3 + 0] - pix;
    dY[p] = pc[(b * 64 + p) * 3 + 1] - piy;
    dZ[p] = pc[(b * 64 + p) * 3 + 2] - piz;
  }
  __syncthreads();

  const float dlx = dX[lane], dly = dY[lane], dlz = dZ[lane];
  const float wl  = __builtin_amdgcn_exp2f(m2[lane]); // exp2(A_il[l]) per-lane
  const float aij = m0[lane];                          // lane also plays j here
  float* sTw = sT + wu * 128;
  float acc = 0.f;

  for (int kk0 = 2 * wu; kk0 < 64; kk0 += 8) {
    const int kk = __builtin_amdgcn_readfirstlane(kk0);
    v2f cx2[2], cy2[2], cz2[2], mm2[2];
#pragma unroll
    for (int t = 0; t < 2; ++t) {
      const int k = kk + t;
      const float dkx = dX[k], dky = dY[k], dkz = dZ[k];  // broadcast
      const float cx = dky * dlz - dkz * dly;             // d_k x d_l (per-lane)
      const float cy = dkz * dlx - dkx * dlz;
      const float cz = dkx * dly - dky * dlx;
      cx2[t] = (v2f){cx, cx};
      cy2[t] = (v2f){cy, cy};
      cz2[t] = (v2f){cz, cz};
      const float mv = m5[k * 64 + lane] * wl;            // R_kl * w_il
      mm2[t] = (v2f){mv, mv};
      // T row for this k (lane plays j): exp2(a_ij + a_jk + a_ik)
      const float Tv = __builtin_amdgcn_exp2f(aij + m3[k * 64 + lane] + m1[k]);
      sTw[t * 64 + lane] = Tv;
    }
    // same-wave LDS write->read: compiler inserts lgkmcnt wait; no barrier.
#pragma unroll 2
    for (int jp = 0; jp < 32; ++jp) {
      const v2f xx = *(const v2f*)&sD[jp * 8 + 0];     // broadcast b64
      const v2f yy = *(const v2f*)&sD[jp * 8 + 2];
      const v2f zz = *(const v2f*)&sD[jp * 8 + 4];
      const v2f E01 = *(const v2f*)&sE[jp * 128 + lane * 2]; // per-lane b64
      v2f Tt[2];
      Tt[0] = *(const v2f*)&sTw[2 * jp];        // broadcast b64
      Tt[1] = *(const v2f*)&sTw[64 + 2 * jp];
#pragma unroll
      for (int t = 0; t < 2; ++t) {
        v2f e01 = E01 * mm2[t];
        v2f x01 = __builtin_elementwise_fma(Tt[t], e01, (v2f){1.f, 1.f});
        v2f det = __builtin_elementwise_fma(xx, cx2[t],
                    __builtin_elementwise_fma(yy, cy2[t], zz * cz2[t]));
        v2f d2  = det * det;
        float den = x01.x * x01.y;
        float rd  = __builtin_amdgcn_rcpf(den);
        float num = fmaf(d2.x, x01.y, d2.y * x01.x);
        acc = fmaf(num, rd, acc);
      }
    }
  }

  // reduce: lanes sum over l; waves sum over their k slices
  for (int s = 32; s; s >>= 1) acc += __shfl_xor(acc, s, 64);
  if (lane == 0) wsum[wu] = acc;
  __syncthreads();
  if (tid == 0) {
    float blocksum = wsum[0] + wsum[1] + wsum[2] + wsum[3];
    atomicAdd(&pooled[b], blocksum * (1.f / 16777216.f)); // / N^4
  }
}

// ---------------------------------------------------------------------------
// Final tiny MLP: out[b] = gelu_tanh(pooled[b]*W1 + b1) @ W2 + b2
// ---------------------------------------------------------------------------
__global__ void simplex_final(
    const float* __restrict__ pooled,
    const float* __restrict__ W1, const float* __restrict__ b1,
    const float* __restrict__ W2, const float* __restrict__ b2,
    float* __restrict__ out)
{
  int t = threadIdx.x;
  if (t < BB) {
    float x = pooled[t];
    float o = b2[0];
    for (int c = 0; c < 32; ++c) {
      float z  = fmaf(x, W1[c], b1[c]);
      float z3 = z * z * z;
      float y  = 0.7978845608028654f * fmaf(0.044715f, z3, z);
      float ay = fabsf(y);
      float e  = __builtin_amdgcn_exp2f(2.8853900817779268f * ay);
      float th = 1.f - 2.f / (e + 1.f);
      th = copysignf(th, y);
      float gl = 0.5f * z * (1.f + th);
      o = fmaf(gl, W2[c], o);
    }
    out[t] = o;
  }
}

// ---------------------------------------------------------------------------
extern "C" void kernel_launch(void* const* d_in, const int* in_sizes, int n_in,
                              void* d_out, int out_size, void* d_ws, size_t ws_size,
                              hipStream_t stream) {
  (void)in_sizes; (void)n_in; (void)out_size; (void)ws_size;
  const float* pc  = (const float*)d_in[0];
  const float* Wq  = (const float*)d_in[1];
  const float* bq  = (const float*)d_in[2];
  const float* Wk1 = (const float*)d_in[3];
  const float* bk1 = (const float*)d_in[4];
  const float* Wk2 = (const float*)d_in[5];
  const float* bk2 = (const float*)d_in[6];
  const float* Wk3 = (const float*)d_in[7];
  const float* bk3 = (const float*)d_in[8];
  const float* W1  = (const float*)d_in[9];
  const float* b1  = (const float*)d_in[10];
  const float* W2  = (const float*)d_in[11];
  const float* b2  = (const float*)d_in[12];

  float* ws     = (float*)d_ws;
  float* pooled = ws + POOLED_OFF;
  float* out    = (float*)d_out;

  hipLaunchKernelGGL(simplex_phase1, dim3(BB * 7), dim3(256), 0, stream,
                     pc, Wq, bq, Wk1, bk1, Wk2, bk2, Wk3, bk3, ws);
  hipLaunchKernelGGL(simplex_main, dim3(BB * NN), dim3(256), 0, stream,
                     pc, ws, pooled);
  hipLaunchKernelGGL(simplex_final, dim3(1), dim3(64), 0, stream,
                     pooled, W1, b1, W2, b2, out);
}